// Round 4
// baseline (1293.347 us; speedup 1.0000x reference)
//
#include <hip/hip_runtime.h>
#include <math.h>

#define N_NODES 100000
#define N_EDGES 3200000
#define SCAN_NB ((N_NODES + 255) / 256)   // 391
#define PLANE 800000                      // floats per feature-half plane (N*8)

// Sharded scatter: 8 dst-shards (one per XCD via blockIdx%8 round-robin heuristic)
#define N_SHARDS 8
#define NODES_PER_SHARD (N_NODES / N_SHARDS)   // 12500
#define N_CHUNKS 800
#define EDGES_PER_CHUNK (N_EDGES / N_CHUNKS)   // 4000

// ---------------- CSR build ----------------

__global__ void k_init(int* __restrict__ count) {
    int i = blockIdx.x * blockDim.x + threadIdx.x;
    if (i < N_NODES) count[i] = 0;
}

__global__ void k_hist(const int* __restrict__ dst, int* __restrict__ count) {
    int e = blockIdx.x * blockDim.x + threadIdx.x;   // grid sized exactly E
    int d = __builtin_nontemporal_load(&dst[e]);
    atomicAdd(&count[d], 1);
}

__global__ __launch_bounds__(256) void k_scan1(const int* __restrict__ count,
                                               int* __restrict__ row_start,
                                               int* __restrict__ bsum) {
    __shared__ int tmp[256];
    const int t = threadIdx.x;
    const int i = blockIdx.x * 256 + t;
    int v = (i < N_NODES) ? count[i] : 0;
    tmp[t] = v;
    __syncthreads();
    for (int off = 1; off < 256; off <<= 1) {
        int a = (t >= off) ? tmp[t - off] : 0;
        __syncthreads();
        tmp[t] += a;
        __syncthreads();
    }
    if (i < N_NODES) row_start[i] = tmp[t] - v;   // exclusive
    if (t == 255) bsum[blockIdx.x] = tmp[255];
}

__global__ __launch_bounds__(512) void k_scan2(int* __restrict__ bsum) {
    __shared__ int tmp[512];
    const int t = threadIdx.x;
    int v = (t < SCAN_NB) ? bsum[t] : 0;
    tmp[t] = v;
    __syncthreads();
    for (int off = 1; off < 512; off <<= 1) {
        int a = (t >= off) ? tmp[t - off] : 0;
        __syncthreads();
        tmp[t] += a;
        __syncthreads();
    }
    if (t < SCAN_NB) bsum[t] = tmp[t] - v;   // exclusive
}

__global__ __launch_bounds__(256) void k_scan3(const int* __restrict__ count,
                                               int* __restrict__ row_start,
                                               const int* __restrict__ bsum,
                                               int* __restrict__ cursor,
                                               float* __restrict__ dinv) {
    const int i = blockIdx.x * 256 + threadIdx.x;
    if (i >= N_NODES) return;
    int rs = row_start[i] + bsum[blockIdx.x];
    row_start[i] = rs;
    cursor[i] = rs;
    dinv[i] = 1.0f / sqrtf((float)(count[i] + 1));   // deg includes self-loop
}

// Sharded scatter; nontemporal loads keep the streaming dst/src reads from
// evicting the shard's partially-filled csr lines out of the XCD L2.
__global__ __launch_bounds__(256) void k_scatter(const int* __restrict__ src,
                                                 const int* __restrict__ dst,
                                                 int* __restrict__ cursor,
                                                 int* __restrict__ csr_src) {
    const int shard = blockIdx.x & (N_SHARDS - 1);
    const int chunk = blockIdx.x >> 3;
    const int lo = shard * NODES_PER_SHARD;
    const int hi = lo + NODES_PER_SHARD;
    const int e0 = chunk * EDGES_PER_CHUNK;
    const int e1 = e0 + EDGES_PER_CHUNK;
    for (int e = e0 + threadIdx.x; e < e1; e += 256) {
        int d = __builtin_nontemporal_load(&dst[e]);
        if (d >= lo && d < hi) {
            int s = __builtin_nontemporal_load(&src[e]);
            int pos = atomicAdd(&cursor[d], 1);
            csr_src[pos] = s;
        }
    }
}

// ---------------- MLP 131->64->32->16, fused with first conv transform ----------------
// All k-loops over register arrays fully unrolled (constant indices -> no scratch
// spill; R3's VGPR=68 + 45 GB scratch traffic came from partial unrolls).
// Writes u0 in feature-half planes: up[half*PLANE + node*8 + f].

__global__ __launch_bounds__(256, 2) void k_mlp(
        const float* __restrict__ x,
        const float* __restrict__ W1, const float* __restrict__ b1,
        const float* __restrict__ W2, const float* __restrict__ b2,
        const float* __restrict__ W3, const float* __restrict__ b3,
        const float* __restrict__ Wc1,
        const float* __restrict__ dinv,
        float* __restrict__ up) {
    int node = blockIdx.x * 256 + threadIdx.x;
    if (node >= N_NODES) return;

    const float* xr = x + (long)node * 131;

    float a1[64];
#pragma unroll
    for (int j = 0; j < 64; ++j) a1[j] = b1[j];
    for (int k = 0; k < 131; ++k) {        // rolled: a1 indices stay constant
        float xk = xr[k];
        const float* wr = W1 + k * 64;
#pragma unroll
        for (int j = 0; j < 64; ++j) a1[j] += xk * wr[j];
    }
#pragma unroll
    for (int j = 0; j < 64; ++j) a1[j] = tanhf(a1[j]);

    float a2[32];
#pragma unroll
    for (int j = 0; j < 32; ++j) a2[j] = b2[j];
#pragma unroll
    for (int k = 0; k < 64; ++k) {         // fully unrolled
        float hk = a1[k];
#pragma unroll
        for (int j = 0; j < 32; ++j) a2[j] += hk * W2[k * 32 + j];
    }
#pragma unroll
    for (int j = 0; j < 32; ++j) a2[j] = tanhf(a2[j]);

    float a3[16];
#pragma unroll
    for (int j = 0; j < 16; ++j) a3[j] = b3[j];
#pragma unroll
    for (int k = 0; k < 32; ++k) {         // fully unrolled
        float hk = a2[k];
#pragma unroll
        for (int j = 0; j < 16; ++j) a3[j] += hk * W3[k * 16 + j];
    }
    // u0 = (h3 @ Wc1) * dinv   (conv bias applied during aggregation)
    float dv = dinv[node];
    float uo[16];
#pragma unroll
    for (int j = 0; j < 16; ++j) uo[j] = 0.0f;
#pragma unroll
    for (int k = 0; k < 16; ++k) {
        float hk = a3[k];
#pragma unroll
        for (int j = 0; j < 16; ++j) uo[j] += hk * Wc1[k * 16 + j];
    }
    float4* p0 = reinterpret_cast<float4*>(up + (long)node * 8);
    float4* p1 = reinterpret_cast<float4*>(up + PLANE + (long)node * 8);
    float4 v;
    v.x = uo[0] * dv; v.y = uo[1] * dv; v.z = uo[2] * dv; v.w = uo[3] * dv; p0[0] = v;
    v.x = uo[4] * dv; v.y = uo[5] * dv; v.z = uo[6] * dv; v.w = uo[7] * dv; p0[1] = v;
    v.x = uo[8] * dv; v.y = uo[9] * dv; v.z = uo[10] * dv; v.w = uo[11] * dv; p1[0] = v;
    v.x = uo[12] * dv; v.y = uo[13] * dv; v.z = uo[14] * dv; v.w = uo[15] * dv; p1[1] = v;
}

// ---------------- Aggregation over one feature-half plane ----------------
// shard = blockIdx%8 -> XCD affinity: half = shard&1 (3.2 MB u-plane, L2-resident),
// node-quarter = shard>>1. 2 nodes per wave: f = lane&7, grp = (lane>>3)&3,
// node-select = lane>>5. h[half][i][f] = tanh(dinv*(sum_e u[src][f] + u[i][f]) + b[f])

__global__ __launch_bounds__(256) void k_aggh(
        const float* __restrict__ up,
        const int* __restrict__ row_start,
        const int* __restrict__ count,
        const int* __restrict__ csr_src,
        const float* __restrict__ dinv,
        const float* __restrict__ bias,
        float* __restrict__ hp) {
    const int shard = blockIdx.x & 7;
    const int half = shard & 1;
    const int quarter = shard >> 1;
    const int wave = threadIdx.x >> 6;
    const int lane = threadIdx.x & 63;
    const int f = lane & 7;
    const int grp = (lane >> 3) & 3;
    const int nsel = lane >> 5;
    const int node = quarter * 25000 + (blockIdx.x >> 3) * 8 + wave * 2 + nsel;

    const float* u = up + half * PLANE;
    const int rs = row_start[node];
    const int cnt = count[node];
    const float dv = dinv[node];

    int cmax = max(cnt, __shfl_xor(cnt, 32, 64));   // wave-uniform loop bound

    float acc = 0.0f;
    for (int base = 0; base < cmax; base += 32) {
        // 2x32 coalesced index load (one 32-lane segment per node)
        int idx = csr_src[rs + base + (lane & 31)];
#pragma unroll
        for (int k = 0; k < 8; ++k) {
            int e = base + 4 * k + grp;
            int s = __shfl(idx, (lane & 32) + 4 * k + grp, 64);
            if (e < cnt) acc += u[s * 8 + f];
        }
    }
    // reduce the 4 edge-groups (lane bits 3,4) within each node
    acc += __shfl_xor(acc, 8, 64);
    acc += __shfl_xor(acc, 16, 64);
    acc += u[node * 8 + f];                 // self-loop (u already dinv[src]-scaled)

    float hn = tanhf(dv * acc + bias[half * 8 + f]);
    if (grp == 0) hp[half * PLANE + node * 8 + f] = hn;
}

// ---------------- Per-node 16x16 transform (full feature rows) ----------------
// mode 0: u_next planes = (h @ W) * dinv
// mode 1: out[0..2N) = h @ Wcls + bcls; out[2N..) = h row-major

__global__ __launch_bounds__(256) void k_trans(
        const float* __restrict__ hp,
        const float* __restrict__ dinv,
        const float* __restrict__ W,
        const float* __restrict__ bcls,
        float* __restrict__ up_next,
        float* __restrict__ out,
        int mode) {
    int node = blockIdx.x * 256 + threadIdx.x;
    if (node >= N_NODES) return;

    const float4* p0 = reinterpret_cast<const float4*>(hp + (long)node * 8);
    const float4* p1 = reinterpret_cast<const float4*>(hp + PLANE + (long)node * 8);
    float4 ha = p0[0], hb = p0[1], hc = p1[0], hd = p1[1];
    float h[16] = {ha.x, ha.y, ha.z, ha.w, hb.x, hb.y, hb.z, hb.w,
                   hc.x, hc.y, hc.z, hc.w, hd.x, hd.y, hd.z, hd.w};

    if (mode == 0) {
        float dv = dinv[node];
        float o[16];
#pragma unroll
        for (int j = 0; j < 16; ++j) o[j] = 0.0f;
#pragma unroll
        for (int k = 0; k < 16; ++k) {
            float hk = h[k];
#pragma unroll
            for (int j = 0; j < 16; ++j) o[j] += hk * W[k * 16 + j];
        }
        float4* q0 = reinterpret_cast<float4*>(up_next + (long)node * 8);
        float4* q1 = reinterpret_cast<float4*>(up_next + PLANE + (long)node * 8);
        float4 v;
        v.x = o[0] * dv; v.y = o[1] * dv; v.z = o[2] * dv; v.w = o[3] * dv; q0[0] = v;
        v.x = o[4] * dv; v.y = o[5] * dv; v.z = o[6] * dv; v.w = o[7] * dv; q0[1] = v;
        v.x = o[8] * dv; v.y = o[9] * dv; v.z = o[10] * dv; v.w = o[11] * dv; q1[0] = v;
        v.x = o[12] * dv; v.y = o[13] * dv; v.z = o[14] * dv; v.w = o[15] * dv; q1[1] = v;
    } else {
        float c0 = bcls[0], c1 = bcls[1];
#pragma unroll
        for (int k = 0; k < 16; ++k) {
            c0 += h[k] * W[k * 2 + 0];
            c1 += h[k] * W[k * 2 + 1];
        }
        out[(long)node * 2 + 0] = c0;
        out[(long)node * 2 + 1] = c1;
        float4* ho = reinterpret_cast<float4*>(out + 200000 + (long)node * 16);
        ho[0] = ha; ho[1] = hb; ho[2] = hc; ho[3] = hd;
    }
}

// ---------------- launch ----------------

extern "C" void kernel_launch(void* const* d_in, const int* in_sizes, int n_in,
                              void* d_out, int out_size, void* d_ws, size_t ws_size,
                              hipStream_t stream) {
    const float* x    = (const float*)d_in[0];
    const int*   ei   = (const int*)d_in[1];
    const float* W1   = (const float*)d_in[2];
    const float* b1   = (const float*)d_in[3];
    const float* W2   = (const float*)d_in[4];
    const float* b2   = (const float*)d_in[5];
    const float* W3   = (const float*)d_in[6];
    const float* b3   = (const float*)d_in[7];
    const float* Wc1  = (const float*)d_in[8];
    const float* bc1  = (const float*)d_in[9];
    const float* Wg   = (const float*)d_in[10];
    const float* bg   = (const float*)d_in[11];
    const float* Wcls = (const float*)d_in[12];
    const float* bcls = (const float*)d_in[13];
    float* out = (float*)d_out;

    const int* src = ei;
    const int* dst = ei + N_EDGES;

    // workspace layout (4B words; u/h planes land 64B-aligned)
    int* count     = (int*)d_ws;
    int* cursor    = count + N_NODES;
    int* row_start = cursor + N_NODES;
    float* dinv    = (float*)(row_start + N_NODES);
    int* csr_src   = (int*)(dinv + N_NODES);
    float* u       = (float*)(csr_src + N_EDGES);   // 2 planes of N*8 floats
    float* hp      = u + 2 * PLANE;                 // 2 planes of N*8 floats
    // bsum aliases csr_src[0..511]: consumed by k_scan3 before k_scatter writes
    int* bsum      = csr_src;

    k_init<<<(N_NODES + 255) / 256, 256, 0, stream>>>(count);
    k_hist<<<N_EDGES / 256, 256, 0, stream>>>(dst, count);
    k_scan1<<<SCAN_NB, 256, 0, stream>>>(count, row_start, bsum);
    k_scan2<<<1, 512, 0, stream>>>(bsum);
    k_scan3<<<SCAN_NB, 256, 0, stream>>>(count, row_start, bsum, cursor, dinv);
    k_scatter<<<N_CHUNKS * N_SHARDS, 256, 0, stream>>>(src, dst, cursor, csr_src);
    k_mlp<<<(N_NODES + 255) / 256, 256, 0, stream>>>(x, W1, b1, W2, b2, W3, b3,
                                                     Wc1, dinv, u);

    for (int j = 0; j < 10; ++j) {
        const float* bias = (j < 5) ? bc1 : (bg + (long)(j - 5) * 16);
        k_aggh<<<25000, 256, 0, stream>>>(u, row_start, count, csr_src, dinv, bias, hp);
        if (j < 9) {
            const float* Wn = (j < 4) ? Wc1 : (Wg + (long)(j - 4) * 256);
            k_trans<<<SCAN_NB, 256, 0, stream>>>(hp, dinv, Wn, nullptr, u, nullptr, 0);
        } else {
            k_trans<<<SCAN_NB, 256, 0, stream>>>(hp, dinv, Wcls, bcls, nullptr, out, 1);
        }
    }
}

// Round 5
// 1221.813 us; speedup vs baseline: 1.0585x; 1.0585x over previous
//
#include <hip/hip_runtime.h>
#include <math.h>

#define N_NODES 100000
#define N_EDGES 3200000
#define SCAN_NB ((N_NODES + 255) / 256)   // 391
#define PLANE 800000                      // floats per feature-half plane (N*8)

// Sharded scatter: 8 dst-shards (one per XCD via blockIdx%8 round-robin heuristic)
#define N_SHARDS 8
#define NODES_PER_SHARD (N_NODES / N_SHARDS)   // 12500
#define N_CHUNKS 800
#define EDGES_PER_CHUNK (N_EDGES / N_CHUNKS)   // 4000

// ---------------- CSR build ----------------

__global__ void k_init(int* __restrict__ count) {
    int i = blockIdx.x * blockDim.x + threadIdx.x;
    if (i < N_NODES) count[i] = 0;
}

__global__ void k_hist(const int* __restrict__ dst, int* __restrict__ count) {
    int e = blockIdx.x * blockDim.x + threadIdx.x;   // grid sized exactly E
    int d = __builtin_nontemporal_load(&dst[e]);
    atomicAdd(&count[d], 1);
}

__global__ __launch_bounds__(256) void k_scan1(const int* __restrict__ count,
                                               int* __restrict__ row_start,
                                               int* __restrict__ bsum) {
    __shared__ int tmp[256];
    const int t = threadIdx.x;
    const int i = blockIdx.x * 256 + t;
    int v = (i < N_NODES) ? count[i] : 0;
    tmp[t] = v;
    __syncthreads();
    for (int off = 1; off < 256; off <<= 1) {
        int a = (t >= off) ? tmp[t - off] : 0;
        __syncthreads();
        tmp[t] += a;
        __syncthreads();
    }
    if (i < N_NODES) row_start[i] = tmp[t] - v;   // exclusive
    if (t == 255) bsum[blockIdx.x] = tmp[255];
}

__global__ __launch_bounds__(512) void k_scan2(int* __restrict__ bsum) {
    __shared__ int tmp[512];
    const int t = threadIdx.x;
    int v = (t < SCAN_NB) ? bsum[t] : 0;
    tmp[t] = v;
    __syncthreads();
    for (int off = 1; off < 512; off <<= 1) {
        int a = (t >= off) ? tmp[t - off] : 0;
        __syncthreads();
        tmp[t] += a;
        __syncthreads();
    }
    if (t < SCAN_NB) bsum[t] = tmp[t] - v;   // exclusive
}

__global__ __launch_bounds__(256) void k_scan3(const int* __restrict__ count,
                                               int* __restrict__ row_start,
                                               const int* __restrict__ bsum,
                                               int* __restrict__ cursor,
                                               float* __restrict__ dinv) {
    const int i = blockIdx.x * 256 + threadIdx.x;
    if (i >= N_NODES) return;
    int rs = row_start[i] + bsum[blockIdx.x];
    row_start[i] = rs;
    cursor[i] = rs;
    dinv[i] = 1.0f / sqrtf((float)(count[i] + 1));   // deg includes self-loop
}

__global__ __launch_bounds__(256) void k_scatter(const int* __restrict__ src,
                                                 const int* __restrict__ dst,
                                                 int* __restrict__ cursor,
                                                 int* __restrict__ csr_src) {
    const int shard = blockIdx.x & (N_SHARDS - 1);
    const int chunk = blockIdx.x >> 3;
    const int lo = shard * NODES_PER_SHARD;
    const int hi = lo + NODES_PER_SHARD;
    const int e0 = chunk * EDGES_PER_CHUNK;
    const int e1 = e0 + EDGES_PER_CHUNK;
    for (int e = e0 + threadIdx.x; e < e1; e += 256) {
        int d = __builtin_nontemporal_load(&dst[e]);
        if (d >= lo && d < hi) {
            int s = __builtin_nontemporal_load(&src[e]);
            int pos = atomicAdd(&cursor[d], 1);
            csr_src[pos] = s;
        }
    }
}

// ---------------- MLP 131->64->32->16, fused with first conv transform ----------------
// Anti-spill structure: layer-1 computed in 4 chunks of 16 outputs (only 16
// accumulators live), each chunk parked in a PRIVATE per-thread LDS row
// (stride 65 -> 2-way bank aliasing = free; no cross-thread sharing, no barrier).
// Layer 2 streams h1 back from LDS into a2[32]; layers 3 + conv-fuse stay in
// registers (<=48 floats live). Weight addresses are wave-uniform -> s_load,
// so FMAs read weights from SGPRs (no VGPR cost).

__global__ __launch_bounds__(256) void k_mlp(
        const float* __restrict__ x,
        const float* __restrict__ W1, const float* __restrict__ b1,
        const float* __restrict__ W2, const float* __restrict__ b2,
        const float* __restrict__ W3, const float* __restrict__ b3,
        const float* __restrict__ Wc1,
        const float* __restrict__ dinv,
        float* __restrict__ up) {
    __shared__ float h1s[256 * 65];   // 66.5 KB: private row per thread
    const int t = threadIdx.x;
    const int node = blockIdx.x * 256 + t;
    if (node >= N_NODES) return;      // safe: no __syncthreads in this kernel

    const float* xr = x + (long)node * 131;
    float* myrow = h1s + t * 65;

    // ---- layer 1: 4 chunks of 16 outputs ----
    for (int c = 0; c < 4; ++c) {
        const float* W1c = W1 + c * 16;
        float a[16];
#pragma unroll
        for (int j = 0; j < 16; ++j) a[j] = b1[c * 16 + j];
        for (int k = 0; k < 131; ++k) {
            float xk = xr[k];
            const float* wr = W1c + k * 64;   // wave-uniform -> s_load
#pragma unroll
            for (int j = 0; j < 16; ++j) a[j] += xk * wr[j];
        }
#pragma unroll
        for (int j = 0; j < 16; ++j) myrow[c * 16 + j] = tanhf(a[j]);
    }

    // ---- layer 2: stream h1 from LDS ----
    float a2[32];
#pragma unroll
    for (int j = 0; j < 32; ++j) a2[j] = b2[j];
    for (int k = 0; k < 64; ++k) {
        float hk = myrow[k];
        const float* wr = W2 + k * 32;        // wave-uniform -> s_load
#pragma unroll
        for (int j = 0; j < 32; ++j) a2[j] += hk * wr[j];
    }
#pragma unroll
    for (int j = 0; j < 32; ++j) a2[j] = tanhf(a2[j]);

    // ---- layer 3 (no tanh) ----
    float a3[16];
#pragma unroll
    for (int j = 0; j < 16; ++j) a3[j] = b3[j];
#pragma unroll 4
    for (int k = 0; k < 32; ++k) {
        float hk = a2[k];
        const float* wr = W3 + k * 16;
#pragma unroll
        for (int j = 0; j < 16; ++j) a3[j] += hk * wr[j];
    }

    // ---- conv-fuse: u0 = (h3 @ Wc1) * dinv ----
    float dv = dinv[node];
    float uo[16];
#pragma unroll
    for (int j = 0; j < 16; ++j) uo[j] = 0.0f;
#pragma unroll 4
    for (int k = 0; k < 16; ++k) {
        float hk = a3[k];
        const float* wr = Wc1 + k * 16;
#pragma unroll
        for (int j = 0; j < 16; ++j) uo[j] += hk * wr[j];
    }
    float4* p0 = reinterpret_cast<float4*>(up + (long)node * 8);
    float4* p1 = reinterpret_cast<float4*>(up + PLANE + (long)node * 8);
    float4 v;
    v.x = uo[0] * dv; v.y = uo[1] * dv; v.z = uo[2] * dv; v.w = uo[3] * dv; p0[0] = v;
    v.x = uo[4] * dv; v.y = uo[5] * dv; v.z = uo[6] * dv; v.w = uo[7] * dv; p0[1] = v;
    v.x = uo[8] * dv; v.y = uo[9] * dv; v.z = uo[10] * dv; v.w = uo[11] * dv; p1[0] = v;
    v.x = uo[12] * dv; v.y = uo[13] * dv; v.z = uo[14] * dv; v.w = uo[15] * dv; p1[1] = v;
}

// ---------------- Aggregation over one feature-half plane ----------------

__global__ __launch_bounds__(256) void k_aggh(
        const float* __restrict__ up,
        const int* __restrict__ row_start,
        const int* __restrict__ count,
        const int* __restrict__ csr_src,
        const float* __restrict__ dinv,
        const float* __restrict__ bias,
        float* __restrict__ hp) {
    const int shard = blockIdx.x & 7;
    const int half = shard & 1;
    const int quarter = shard >> 1;
    const int wave = threadIdx.x >> 6;
    const int lane = threadIdx.x & 63;
    const int f = lane & 7;
    const int grp = (lane >> 3) & 3;
    const int nsel = lane >> 5;
    const int node = quarter * 25000 + (blockIdx.x >> 3) * 8 + wave * 2 + nsel;

    const float* u = up + half * PLANE;
    const int rs = row_start[node];
    const int cnt = count[node];
    const float dv = dinv[node];

    int cmax = max(cnt, __shfl_xor(cnt, 32, 64));   // wave-uniform loop bound

    float acc = 0.0f;
    for (int base = 0; base < cmax; base += 32) {
        int idx = csr_src[rs + base + (lane & 31)];
#pragma unroll
        for (int k = 0; k < 8; ++k) {
            int e = base + 4 * k + grp;
            int s = __shfl(idx, (lane & 32) + 4 * k + grp, 64);
            if (e < cnt) acc += u[s * 8 + f];
        }
    }
    acc += __shfl_xor(acc, 8, 64);
    acc += __shfl_xor(acc, 16, 64);
    acc += u[node * 8 + f];                 // self-loop (u already dinv[src]-scaled)

    float hn = tanhf(dv * acc + bias[half * 8 + f]);
    if (grp == 0) hp[half * PLANE + node * 8 + f] = hn;
}

// ---------------- Per-node 16x16 transform (full feature rows) ----------------

__global__ __launch_bounds__(256) void k_trans(
        const float* __restrict__ hp,
        const float* __restrict__ dinv,
        const float* __restrict__ W,
        const float* __restrict__ bcls,
        float* __restrict__ up_next,
        float* __restrict__ out,
        int mode) {
    int node = blockIdx.x * 256 + threadIdx.x;
    if (node >= N_NODES) return;

    const float4* p0 = reinterpret_cast<const float4*>(hp + (long)node * 8);
    const float4* p1 = reinterpret_cast<const float4*>(hp + PLANE + (long)node * 8);
    float4 ha = p0[0], hb = p0[1], hc = p1[0], hd = p1[1];
    float h[16] = {ha.x, ha.y, ha.z, ha.w, hb.x, hb.y, hb.z, hb.w,
                   hc.x, hc.y, hc.z, hc.w, hd.x, hd.y, hd.z, hd.w};

    if (mode == 0) {
        float dv = dinv[node];
        float o[16];
#pragma unroll
        for (int j = 0; j < 16; ++j) o[j] = 0.0f;
#pragma unroll 4
        for (int k = 0; k < 16; ++k) {
            float hk = h[k];
#pragma unroll
            for (int j = 0; j < 16; ++j) o[j] += hk * W[k * 16 + j];
        }
        float4* q0 = reinterpret_cast<float4*>(up_next + (long)node * 8);
        float4* q1 = reinterpret_cast<float4*>(up_next + PLANE + (long)node * 8);
        float4 v;
        v.x = o[0] * dv; v.y = o[1] * dv; v.z = o[2] * dv; v.w = o[3] * dv; q0[0] = v;
        v.x = o[4] * dv; v.y = o[5] * dv; v.z = o[6] * dv; v.w = o[7] * dv; q0[1] = v;
        v.x = o[8] * dv; v.y = o[9] * dv; v.z = o[10] * dv; v.w = o[11] * dv; q1[0] = v;
        v.x = o[12] * dv; v.y = o[13] * dv; v.z = o[14] * dv; v.w = o[15] * dv; q1[1] = v;
    } else {
        float c0 = bcls[0], c1 = bcls[1];
#pragma unroll
        for (int k = 0; k < 16; ++k) {
            c0 += h[k] * W[k * 2 + 0];
            c1 += h[k] * W[k * 2 + 1];
        }
        out[(long)node * 2 + 0] = c0;
        out[(long)node * 2 + 1] = c1;
        float4* ho = reinterpret_cast<float4*>(out + 200000 + (long)node * 16);
        ho[0] = ha; ho[1] = hb; ho[2] = hc; ho[3] = hd;
    }
}

// ---------------- launch ----------------

extern "C" void kernel_launch(void* const* d_in, const int* in_sizes, int n_in,
                              void* d_out, int out_size, void* d_ws, size_t ws_size,
                              hipStream_t stream) {
    const float* x    = (const float*)d_in[0];
    const int*   ei   = (const int*)d_in[1];
    const float* W1   = (const float*)d_in[2];
    const float* b1   = (const float*)d_in[3];
    const float* W2   = (const float*)d_in[4];
    const float* b2   = (const float*)d_in[5];
    const float* W3   = (const float*)d_in[6];
    const float* b3   = (const float*)d_in[7];
    const float* Wc1  = (const float*)d_in[8];
    const float* bc1  = (const float*)d_in[9];
    const float* Wg   = (const float*)d_in[10];
    const float* bg   = (const float*)d_in[11];
    const float* Wcls = (const float*)d_in[12];
    const float* bcls = (const float*)d_in[13];
    float* out = (float*)d_out;

    const int* src = ei;
    const int* dst = ei + N_EDGES;

    int* count     = (int*)d_ws;
    int* cursor    = count + N_NODES;
    int* row_start = cursor + N_NODES;
    float* dinv    = (float*)(row_start + N_NODES);
    int* csr_src   = (int*)(dinv + N_NODES);
    float* u       = (float*)(csr_src + N_EDGES);   // 2 planes of N*8 floats
    float* hp      = u + 2 * PLANE;                 // 2 planes of N*8 floats
    int* bsum      = csr_src;   // consumed by k_scan3 before k_scatter writes

    k_init<<<(N_NODES + 255) / 256, 256, 0, stream>>>(count);
    k_hist<<<N_EDGES / 256, 256, 0, stream>>>(dst, count);
    k_scan1<<<SCAN_NB, 256, 0, stream>>>(count, row_start, bsum);
    k_scan2<<<1, 512, 0, stream>>>(bsum);
    k_scan3<<<SCAN_NB, 256, 0, stream>>>(count, row_start, bsum, cursor, dinv);
    k_scatter<<<N_CHUNKS * N_SHARDS, 256, 0, stream>>>(src, dst, cursor, csr_src);
    k_mlp<<<SCAN_NB, 256, 0, stream>>>(x, W1, b1, W2, b2, W3, b3, Wc1, dinv, u);

    for (int j = 0; j < 10; ++j) {
        const float* bias = (j < 5) ? bc1 : (bg + (long)(j - 5) * 16);
        k_aggh<<<25000, 256, 0, stream>>>(u, row_start, count, csr_src, dinv, bias, hp);
        if (j < 9) {
            const float* Wn = (j < 4) ? Wc1 : (Wg + (long)(j - 4) * 256);
            k_trans<<<SCAN_NB, 256, 0, stream>>>(hp, dinv, Wn, nullptr, u, nullptr, 0);
        } else {
            k_trans<<<SCAN_NB, 256, 0, stream>>>(hp, dinv, Wcls, bcls, nullptr, out, 1);
        }
    }
}